// Round 2
// baseline (21000.769 us; speedup 1.0000x reference)
//
#include <hip/hip_runtime.h>
#include <math.h>

#define NB 2048
#define WD 128
#define TD 300
#define NM 24
#define NJ 48
#define NL 6
#define NCOL 38400       // WD*TD

__device__ __forceinline__ float gelu_f(float v){
    return 0.5f * v * (1.0f + erff(v * 0.70710678118654752f));
}

// ---------------- DFT basis tables ----------------
// Ft[j][t] (48x300): j=2m -> cos(2pi m t/300), j=2m+1 -> -sin(...)   (forward rfft)
// G[t][j]  (300x48): j=2m -> s_m cos, j=2m+1 -> -s_m sin, s_0=1/300 (imag of m=0 ignored -> 0), s_m=2/300
__global__ __launch_bounds__(256) void k_tables(float* __restrict__ Ft, float* __restrict__ G){
    int idx = blockIdx.x*256 + threadIdx.x;
    if (idx >= NJ*TD) return;
    const float w0 = 6.28318530717958647692f / (float)TD;
    {
        int j = idx / TD, t = idx - j*TD;
        int m = j >> 1;
        int r = (m * t) % TD;
        float ang = (float)r * w0;
        Ft[idx] = (j & 1) ? -sinf(ang) : cosf(ang);
    }
    {
        int t = idx / NJ, j = idx - t*NJ;
        int m = j >> 1;
        int r = (m * t) % TD;
        float ang = (float)r * w0;
        float s = (m == 0) ? (1.0f/(float)TD) : (2.0f/(float)TD);
        float v;
        if (j & 1) v = (m == 0) ? 0.0f : -s * sinf(ang);
        else       v = s * cosf(ang);
        G[idx] = v;
    }
}

// ---------------- spectral weight transpose: [l][i][o][m] -> [l][m][i][o] ----------------
__global__ __launch_bounds__(256) void k_wt(const float* __restrict__ wr, const float* __restrict__ wi,
                                            float* __restrict__ Wtr, float* __restrict__ Wti){
    long idx = (long)blockIdx.x*256 + threadIdx.x;
    if (idx >= (long)NL*NM*WD*WD) return;
    int o = (int)(idx & 127);
    int i = (int)((idx >> 7) & 127);
    long rest = idx >> 14;
    int m = (int)(rest % NM);
    int l = (int)(rest / NM);
    long src = (((long)l*WD + i)*WD + o)*NM + m;
    Wtr[idx] = wr[src];
    Wti[idx] = wi[src];
}

// ---------------- encoder ----------------
__global__ __launch_bounds__(256) void k_enc1(const float* __restrict__ p, const float* __restrict__ w1,
                                              const float* __restrict__ b1, float* __restrict__ h1){
    int idx = blockIdx.x*256 + threadIdx.x;
    int b = idx >> 7, k = idx & 127;
    float acc = b1[k];
    #pragma unroll
    for (int j = 0; j < 5; j++) acc += p[b*5+j] * w1[j*WD+k];
    h1[idx] = gelu_f(acc);
}

__global__ __launch_bounds__(256) void k_enc2(const float* __restrict__ h1, const float* __restrict__ w2,
                                              const float* __restrict__ b2, float* __restrict__ h2){
    int idx = blockIdx.x*256 + threadIdx.x;
    int b = idx >> 7, k = idx & 127;
    const float* row = h1 + b*WD;
    float acc = b2[k];
    for (int j = 0; j < WD; j += 4) {
        float4 h4 = *(const float4*)(row + j);
        acc += h4.x * w2[(j+0)*WD+k] + h4.y * w2[(j+1)*WD+k]
             + h4.z * w2[(j+2)*WD+k] + h4.w * w2[(j+3)*WD+k];
    }
    h2[idx] = gelu_f(acc);
}

// x[b][c][t] = h2[b][:] @ w3[:, c*300+t] + b3[c*300+t]   (b local to chunk)
__global__ __launch_bounds__(256) void k_enc3(const float* __restrict__ h2,
        const float* __restrict__ w3, const float* __restrict__ b3,
        float* __restrict__ x){
    __shared__ float ht[WD*68];   // transposed [k][b], padded stride 68
    int tid = threadIdx.x;
    int c0 = blockIdx.x * 256;
    int b0 = blockIdx.y * 64;
    for (int idx = tid; idx < 64*WD; idx += 256) {
        int bb = idx >> 7, kk = idx & 127;
        ht[kk*68 + bb] = h2[(b0+bb)*WD + kk];
    }
    __syncthreads();
    int colg = tid & 31, bg = tid >> 5;
    const float* w3p = w3 + c0 + colg*8;
    float acc[64];
    #pragma unroll
    for (int q = 0; q < 64; q++) acc[q] = 0.0f;
    for (int k = 0; k < WD; k++) {
        float4 wa = *(const float4*)(w3p + k*NCOL);
        float4 wb = *(const float4*)(w3p + k*NCOL + 4);
        float4 ha = *(const float4*)(&ht[k*68 + bg*8]);
        float4 hb = *(const float4*)(&ht[k*68 + bg*8 + 4]);
        float hv[8] = {ha.x,ha.y,ha.z,ha.w,hb.x,hb.y,hb.z,hb.w};
        float wv[8] = {wa.x,wa.y,wa.z,wa.w,wb.x,wb.y,wb.z,wb.w};
        #pragma unroll
        for (int r = 0; r < 8; r++)
            #pragma unroll
            for (int c = 0; c < 8; c++)
                acc[r*8+c] += hv[r]*wv[c];
    }
    float4 bia = *(const float4*)(b3 + c0 + colg*8);
    float4 bib = *(const float4*)(b3 + c0 + colg*8 + 4);
    float bv[8] = {bia.x,bia.y,bia.z,bia.w,bib.x,bib.y,bib.z,bib.w};
    #pragma unroll
    for (int r = 0; r < 8; r++) {
        float* dst = x + (long)(b0 + bg*8 + r)*NCOL + c0 + colg*8;
        *(float4*)(dst)     = make_float4(acc[r*8+0]+bv[0], acc[r*8+1]+bv[1], acc[r*8+2]+bv[2], acc[r*8+3]+bv[3]);
        *(float4*)(dst + 4) = make_float4(acc[r*8+4]+bv[4], acc[r*8+5]+bv[5], acc[r*8+6]+bv[6], acc[r*8+7]+bv[7]);
    }
}

// ---------------- rfft as matmul: X[j][row] = sum_t x[row][t] * Ft[j][t] ----------------
// ROWS = CB*WD (X column stride)
__global__ __launch_bounds__(256) void k_rfft(const float* __restrict__ x,
        const float* __restrict__ Ft, float* __restrict__ X, int ROWS){
    __shared__ float xl[32*TD];
    int tid = threadIdx.x;
    long row0 = (long)blockIdx.x * 32;
    for (int idx = tid; idx < 32*(TD/4); idx += 256) {
        int rr = idx / (TD/4), t4 = idx - rr*(TD/4);
        *(float4*)(&xl[rr*TD + t4*4]) = *(const float4*)(x + (row0+rr)*TD + t4*4);
    }
    __syncthreads();
    int colg = tid & 15, rowg = tid >> 4;
    const float* xr0 = &xl[(rowg*2)*TD];
    const float* xr1 = &xl[(rowg*2+1)*TD];
    const float* f0 = Ft + (colg)*TD;
    const float* f1 = Ft + (colg+16)*TD;
    const float* f2 = Ft + (colg+32)*TD;
    float a00=0,a01=0,a02=0,a10=0,a11=0,a12=0;
    for (int t = 0; t < TD; t += 4) {
        float4 v0 = *(const float4*)(xr0 + t);
        float4 v1 = *(const float4*)(xr1 + t);
        float4 g0 = *(const float4*)(f0 + t);
        float4 g1 = *(const float4*)(f1 + t);
        float4 g2 = *(const float4*)(f2 + t);
        a00 += v0.x*g0.x + v0.y*g0.y + v0.z*g0.z + v0.w*g0.w;
        a01 += v0.x*g1.x + v0.y*g1.y + v0.z*g1.z + v0.w*g1.w;
        a02 += v0.x*g2.x + v0.y*g2.y + v0.z*g2.z + v0.w*g2.w;
        a10 += v1.x*g0.x + v1.y*g0.y + v1.z*g0.z + v1.w*g0.w;
        a11 += v1.x*g1.x + v1.y*g1.y + v1.z*g1.z + v1.w*g1.w;
        a12 += v1.x*g2.x + v1.y*g2.y + v1.z*g2.z + v1.w*g2.w;
    }
    long row = row0 + rowg*2;
    X[(long)(colg   )*ROWS + row  ] = a00;
    X[(long)(colg+16)*ROWS + row  ] = a01;
    X[(long)(colg+32)*ROWS + row  ] = a02;
    X[(long)(colg   )*ROWS + row+1] = a10;
    X[(long)(colg+16)*ROWS + row+1] = a11;
    X[(long)(colg+32)*ROWS + row+1] = a12;
}

// ---------------- per-mode complex channel mix ----------------
// Yr[b][o] = sum_i Xr*Wr - Xi*Wi ; Yi = sum_i Xr*Wi + Xi*Wr ; Y stored [b][o][j] interleaved
__global__ __launch_bounds__(256) void k_mix(const float* __restrict__ X,
        const float* __restrict__ Wtr, const float* __restrict__ Wti,
        float* __restrict__ Y, int layer, int ROWS){
    __shared__ float xrl[WD*36];
    __shared__ float xil[WD*36];
    int tid = threadIdx.x;
    int m = blockIdx.y;
    int b0 = blockIdx.x * 32;
    const float* Xr = X + (long)(2*m  )*ROWS + (long)b0*WD;
    const float* Xi = X + (long)(2*m+1)*ROWS + (long)b0*WD;
    for (int idx = tid; idx < 32*WD; idx += 256) {
        int bb = idx >> 7, i = idx & 127;
        xrl[i*36 + bb] = Xr[bb*WD + i];
        xil[i*36 + bb] = Xi[bb*WD + i];
    }
    __syncthreads();
    int bg = tid & 7, og = tid >> 3;
    const float* wr0 = Wtr + ((long)(layer*NM + m)*WD)*WD + og*4;
    const float* wi0 = Wti + ((long)(layer*NM + m)*WD)*WD + og*4;
    float yr[16], yi[16];
    #pragma unroll
    for (int q = 0; q < 16; q++) { yr[q]=0.0f; yi[q]=0.0f; }
    for (int i = 0; i < WD; i++) {
        float4 xr4 = *(const float4*)(&xrl[i*36 + bg*4]);
        float4 xi4 = *(const float4*)(&xil[i*36 + bg*4]);
        float4 wr4 = *(const float4*)(wr0 + i*WD);
        float4 wi4 = *(const float4*)(wi0 + i*WD);
        float xrv[4] = {xr4.x,xr4.y,xr4.z,xr4.w};
        float xiv[4] = {xi4.x,xi4.y,xi4.z,xi4.w};
        float wrv[4] = {wr4.x,wr4.y,wr4.z,wr4.w};
        float wiv[4] = {wi4.x,wi4.y,wi4.z,wi4.w};
        #pragma unroll
        for (int bb = 0; bb < 4; bb++)
            #pragma unroll
            for (int oo = 0; oo < 4; oo++) {
                yr[bb*4+oo] += xrv[bb]*wrv[oo] - xiv[bb]*wiv[oo];
                yi[bb*4+oo] += xrv[bb]*wiv[oo] + xiv[bb]*wrv[oo];
            }
    }
    #pragma unroll
    for (int bb = 0; bb < 4; bb++)
        #pragma unroll
        for (int oo = 0; oo < 4; oo++) {
            long base = ((long)(b0 + bg*4 + bb)*WD + og*4 + oo)*NJ + 2*m;
            *(float2*)(&Y[base]) = make_float2(yr[bb*4+oo], yi[bb*4+oo]);
        }
}

// ---------------- fused irfft + 1x1 conv + gelu + residual (in-place on x) ----------------
__global__ __launch_bounds__(256) void k_update(const float* __restrict__ Y,
        const float* __restrict__ G, const float* __restrict__ convw,
        const float* __restrict__ convb, float* __restrict__ x, int layer){
    __shared__ float yl[WD*NJ];   // [o][j]
    __shared__ float gl[NJ*64];   // [j][t_local]
    int tid = threadIdx.x;
    int b = blockIdx.y;
    int t0 = blockIdx.x * 64;
    const float* yb = Y + (long)b*WD*NJ;
    for (int idx = tid; idx < (WD*NJ)/4; idx += 256)
        *(float4*)(&yl[idx*4]) = *(const float4*)(yb + idx*4);
    for (int idx = tid; idx < 64*NJ; idx += 256) {
        int tt = idx / NJ, j = idx - tt*NJ;
        int t = t0 + tt;
        if (t < TD) gl[j*64 + tt] = G[t*NJ + j];
    }
    __syncthreads();
    int lane = tid & 63, wv = tid >> 6;
    int tg = lane & 15, og0 = lane >> 4;
    int tt = tg*4;
    int t = t0 + tt;
    bool act = (t < TD);
    float* xb = x + (long)b*WD*TD;
    float out[32];
    #pragma unroll
    for (int pass = 0; pass < 8; pass++) {
        int o = wv*4 + og0 + pass*16;
        if (act) {
            float a0=0.f,a1=0.f,a2=0.f,a3=0.f;
            const float* yo = &yl[o*NJ];
            for (int j = 0; j < NJ; j += 4) {
                float4 yv = *(const float4*)(yo + j);
                float4 g0 = *(const float4*)(&gl[(j+0)*64 + tt]);
                float4 g1 = *(const float4*)(&gl[(j+1)*64 + tt]);
                float4 g2 = *(const float4*)(&gl[(j+2)*64 + tt]);
                float4 g3 = *(const float4*)(&gl[(j+3)*64 + tt]);
                a0 += yv.x*g0.x + yv.y*g1.x + yv.z*g2.x + yv.w*g3.x;
                a1 += yv.x*g0.y + yv.y*g1.y + yv.z*g2.y + yv.w*g3.y;
                a2 += yv.x*g0.z + yv.y*g1.z + yv.z*g2.z + yv.w*g3.z;
                a3 += yv.x*g0.w + yv.y*g1.w + yv.z*g2.w + yv.w*g3.w;
            }
            float cb = convb[layer*WD + o];
            float c0=cb, c1=cb, c2=cb, c3=cb;
            const float* wrow = convw + (long)(layer*WD + o)*WD;
            const float* xt = xb + t;
            for (int c = 0; c < WD; c += 4) {
                float4 w4 = *(const float4*)(wrow + c);
                float4 q0 = *(const float4*)(xt + (c+0)*TD);
                float4 q1 = *(const float4*)(xt + (c+1)*TD);
                float4 q2 = *(const float4*)(xt + (c+2)*TD);
                float4 q3 = *(const float4*)(xt + (c+3)*TD);
                c0 += w4.x*q0.x + w4.y*q1.x + w4.z*q2.x + w4.w*q3.x;
                c1 += w4.x*q0.y + w4.y*q1.y + w4.z*q2.y + w4.w*q3.y;
                c2 += w4.x*q0.z + w4.y*q1.z + w4.z*q2.z + w4.w*q3.z;
                c3 += w4.x*q0.w + w4.y*q1.w + w4.z*q2.w + w4.w*q3.w;
            }
            float4 xres = *(const float4*)(xb + o*TD + t);
            out[pass*4+0] = gelu_f(a0 + c0) + xres.x;
            out[pass*4+1] = gelu_f(a1 + c1) + xres.y;
            out[pass*4+2] = gelu_f(a2 + c2) + xres.z;
            out[pass*4+3] = gelu_f(a3 + c3) + xres.w;
        }
    }
    __syncthreads();
    if (act) {
        #pragma unroll
        for (int pass = 0; pass < 8; pass++) {
            int o = wv*4 + og0 + pass*16;
            *(float4*)(xb + o*TD + t) = make_float4(out[pass*4+0], out[pass*4+1],
                                                    out[pass*4+2], out[pass*4+3]);
        }
    }
}

// ---------------- output projection ----------------
__global__ __launch_bounds__(320) void k_out(const float* __restrict__ x,
        const float* __restrict__ w1, const float* __restrict__ b1,
        const float* __restrict__ w2, const float* __restrict__ b2,
        float* __restrict__ out){
    __shared__ float w1t[WD*64];  // [c][o]
    __shared__ float w2l[192];
    __shared__ float b1l[64];
    int tid = threadIdx.x;
    long b = blockIdx.x;
    for (int idx = tid; idx < WD*64; idx += 320) {
        int o = idx & 63, c = idx >> 6;
        w1t[c*64 + o] = w1[o*WD + c];
    }
    if (tid < 192) w2l[tid] = w2[tid];
    if (tid < 64) b1l[tid] = b1[tid];
    __syncthreads();
    int t = tid;
    if (t >= TD) return;
    const float* xb = x + b*WD*TD;
    float hc[64];
    #pragma unroll
    for (int k = 0; k < 64; k++) hc[k] = b1l[k];
    for (int c = 0; c < WD; c++) {
        float xv = xb[c*TD + t];
        #pragma unroll
        for (int k = 0; k < 64; k += 4) {
            float4 w4 = *(const float4*)(&w1t[c*64 + k]);
            hc[k]   += w4.x*xv;
            hc[k+1] += w4.y*xv;
            hc[k+2] += w4.z*xv;
            hc[k+3] += w4.w*xv;
        }
    }
    float r0 = b2[0], r1 = b2[1], r2 = b2[2];
    #pragma unroll
    for (int k = 0; k < 64; k++) {
        float g = gelu_f(hc[k]);
        r0 += w2l[k]     * g;
        r1 += w2l[64+k]  * g;
        r2 += w2l[128+k] * g;
    }
    long ob = (b*TD + t)*3;
    out[ob+0] = r0; out[ob+1] = r1; out[ob+2] = r2;
}

extern "C" void kernel_launch(void* const* d_in, const int* in_sizes, int n_in,
                              void* d_out, int out_size, void* d_ws, size_t ws_size,
                              hipStream_t stream) {
    const float* params = (const float*)d_in[0];
    const float* enc_w1 = (const float*)d_in[1];
    const float* enc_b1 = (const float*)d_in[2];
    const float* enc_w2 = (const float*)d_in[3];
    const float* enc_b2 = (const float*)d_in[4];
    const float* enc_w3 = (const float*)d_in[5];
    const float* enc_b3 = (const float*)d_in[6];
    const float* spec_wr = (const float*)d_in[7];
    const float* spec_wi = (const float*)d_in[8];
    const float* conv_w  = (const float*)d_in[9];
    const float* conv_b  = (const float*)d_in[10];
    const float* out_w1  = (const float*)d_in[11];
    const float* out_b1  = (const float*)d_in[12];
    const float* out_w2  = (const float*)d_in[13];
    const float* out_b2  = (const float*)d_in[14];
    float* outp = (float*)d_out;

    // --- pick largest chunk size CB (batch samples per pipeline pass) that fits ws ---
    long CB = NB;
    int nchunk = 1;
    while (CB > 64) {
        long floats = CB*WD*TD              // x
                    + 2L*NJ*CB*WD           // Xs, Ys
                    + 2L*NL*NM*WD*WD        // Wtr, Wti
                    + 2L*NJ*TD              // Ft, G
                    + 2L*CB*WD;             // h1, h2
        if (floats * 4 <= (long)ws_size) break;
        CB >>= 1; nchunk <<= 1;
    }

    float* ws  = (float*)d_ws;
    float* x   = ws;
    float* Xs  = x   + (long)CB*WD*TD;
    float* Ys  = Xs  + (long)NJ*CB*WD;
    float* Wtr = Ys  + (long)CB*WD*NJ;
    float* Wti = Wtr + (long)NL*NM*WD*WD;
    float* Ft  = Wti + (long)NL*NM*WD*WD;
    float* G   = Ft  + NJ*TD;
    float* h1  = G   + TD*NJ;
    float* h2  = h1  + (long)CB*WD;

    const int ROWS = (int)(CB*WD);

    k_tables<<<(NJ*TD+255)/256, 256, 0, stream>>>(Ft, G);
    k_wt<<<(NL*NM*WD*WD+255)/256, 256, 0, stream>>>(spec_wr, spec_wi, Wtr, Wti);

    for (int ch = 0; ch < nchunk; ch++) {
        const float* pch = params + (long)ch*CB*5;
        float* outch = outp + (long)ch*CB*TD*3;
        k_enc1<<<(int)(CB*WD)/256, 256, 0, stream>>>(pch, enc_w1, enc_b1, h1);
        k_enc2<<<(int)(CB*WD)/256, 256, 0, stream>>>(h1, enc_w2, enc_b2, h2);
        k_enc3<<<dim3(NCOL/256, (int)CB/64), 256, 0, stream>>>(h2, enc_w3, enc_b3, x);
        for (int l = 0; l < NL; l++) {
            k_rfft<<<ROWS/32, 256, 0, stream>>>(x, Ft, Xs, ROWS);
            k_mix<<<dim3((int)CB/32, NM), 256, 0, stream>>>(Xs, Wtr, Wti, Ys, l, ROWS);
            k_update<<<dim3(5, (int)CB), 256, 0, stream>>>(Ys, G, conv_w, conv_b, x, l);
        }
        k_out<<<(int)CB, 320, 0, stream>>>(x, out_w1, out_b1, out_w2, out_b2, outch);
    }
}

// Round 3
// 5142.385 us; speedup vs baseline: 4.0839x; 4.0839x over previous
//
#include <hip/hip_runtime.h>
#include <math.h>

#define WD 128
#define TD 300
#define TP 320
#define NM 24
#define NJ 48
#define NJP 64
#define NL 6
#define NCOL 38400
#define WSCALE 1024.0f

typedef _Float16 half_t;
typedef _Float16 h8 __attribute__((ext_vector_type(8)));
typedef _Float16 h4v __attribute__((ext_vector_type(4)));
typedef float f4 __attribute__((ext_vector_type(4)));

#define MFMA(a,b,c) __builtin_amdgcn_mfma_f32_16x16x32_f16(a,b,c,0,0,0)

__device__ __forceinline__ float gelu_f(float v){
    return 0.5f * v * (1.0f + erff(v * 0.70710678118654752f));
}

// ---------------- DFT basis tables (fp16) ----------------
// Fth[j][t] (48x320): j=2m -> cos(2pi m t/300), j=2m+1 -> -sin ; t>=300 -> 0
// Gt[t][j]  (320x64): j=2m -> s_m cos, j=2m+1 -> -s_m sin (0 for m=0); j>=48 -> 0
__global__ __launch_bounds__(256) void k_tables(half_t* __restrict__ Fth, half_t* __restrict__ Gt){
    int idx = blockIdx.x*256 + threadIdx.x;
    const float w0 = 6.28318530717958647692f / 300.0f;
    if (idx < NJ*TP) {
        int j = idx / TP, t = idx - j*TP;
        int m = j >> 1;
        float v = 0.0f;
        if (t < TD) {
            int r = (m*t) % TD;
            float ang = (float)r * w0;
            v = (j & 1) ? -sinf(ang) : cosf(ang);
        }
        Fth[idx] = (half_t)v;
    }
    if (idx < TP*NJP) {
        int t = idx / NJP, j = idx - t*NJP;
        float v = 0.0f;
        if (j < NJ) {
            int m = j >> 1;
            int r = (m * (t % TD)) % TD;
            float ang = (float)r * w0;
            float s = (m == 0) ? (1.0f/300.0f) : (2.0f/300.0f);
            if (j & 1) v = (m == 0) ? 0.0f : -s*sinf(ang);
            else       v = s*cosf(ang);
        }
        Gt[idx] = (half_t)v;
    }
}

// ---------------- expanded complex weights: Wxh[l][m][n][k] fp16, x WSCALE ----------------
// n<128: Yr col o=n ; n>=128: Yi col o=n-128.  k<128: Xr (i=k) ; k>=128: Xi (i=k-128)
__global__ __launch_bounds__(256) void k_wx(const float* __restrict__ wr, const float* __restrict__ wi,
                                            half_t* __restrict__ Wxh){
    long idx = (long)blockIdx.x*256 + threadIdx.x;
    if (idx >= (long)NL*NM*256*256) return;
    int k = (int)(idx & 255), n = (int)((idx >> 8) & 255);
    int lm = (int)(idx >> 16);
    int l = lm / NM, m = lm - l*NM;
    int i = k & 127, o = n & 127;
    long src = (((long)(l*WD + i))*WD + o)*NM + m;
    float v;
    if (n < 128) v = (k < 128) ? wr[src] : -wi[src];
    else         v = (k < 128) ? wi[src] :  wr[src];
    Wxh[idx] = (half_t)(v * WSCALE);
}

__global__ __launch_bounds__(256) void k_w3t(const float* __restrict__ w3, half_t* __restrict__ w3t){
    int idx = blockIdx.x*256 + threadIdx.x;
    if (idx >= NCOL*WD) return;
    int k = idx & 127, col = idx >> 7;
    w3t[idx] = (half_t)w3[k*NCOL + col];
}

__global__ __launch_bounds__(256) void k_cwh(const float* __restrict__ cw, half_t* __restrict__ cwh){
    int idx = blockIdx.x*256 + threadIdx.x;
    if (idx >= NL*WD*WD) return;
    cwh[idx] = (half_t)cw[idx];
}

// ---------------- encoder ----------------
__global__ __launch_bounds__(256) void k_enc1(const float* __restrict__ p, const float* __restrict__ w1,
                                              const float* __restrict__ b1, float* __restrict__ h1){
    int idx = blockIdx.x*256 + threadIdx.x;
    int b = idx >> 7, k = idx & 127;
    float acc = b1[k];
    #pragma unroll
    for (int j = 0; j < 5; j++) acc += p[b*5+j] * w1[j*WD+k];
    h1[idx] = gelu_f(acc);
}

__global__ __launch_bounds__(256) void k_enc2(const float* __restrict__ h1, const float* __restrict__ w2,
                                              const float* __restrict__ b2, half_t* __restrict__ h2h){
    int idx = blockIdx.x*256 + threadIdx.x;
    int b = idx >> 7, k = idx & 127;
    const float* row = h1 + b*WD;
    float acc = b2[k];
    for (int j = 0; j < WD; j += 4) {
        float4 h4 = *(const float4*)(row + j);
        acc += h4.x * w2[(j+0)*WD+k] + h4.y * w2[(j+1)*WD+k]
             + h4.z * w2[(j+2)*WD+k] + h4.w * w2[(j+3)*WD+k];
    }
    h2h[idx] = (half_t)gelu_f(acc);
}

// ---------------- enc3 MFMA: x[b][col] = h2[b][:] @ w3t[col][:] + b3[col] ----------------
// writes x fp32 [b][38400] and xt0 fp16 [b][t][c]
__global__ __launch_bounds__(256) void k_enc3(const half_t* __restrict__ h2h, const half_t* __restrict__ w3t,
        const float* __restrict__ b3, float* __restrict__ x, half_t* __restrict__ xt){
    int tid = threadIdx.x;
    int lane = tid & 63, w = tid >> 6;
    int wr = w >> 1, wc = w & 1;
    int c0 = blockIdx.x * 128;
    int b0 = blockIdx.y * 64;
    int ln = lane & 15, lk = lane >> 4;
    f4 zz = {0.f,0.f,0.f,0.f};
    f4 acc[2][4];
    #pragma unroll
    for (int i = 0; i < 2; i++) for (int j = 0; j < 4; j++) acc[i][j] = zz;
    const half_t* ap = h2h + (long)(b0 + wr*32 + ln)*WD + lk*8;
    const half_t* bp = w3t + (long)(c0 + wc*64 + ln)*WD + lk*8;
    #pragma unroll
    for (int ks = 0; ks < 4; ks++) {
        h8 a0 = *(const h8*)(ap + ks*32);
        h8 a1 = *(const h8*)(ap + 16*WD + ks*32);
        #pragma unroll
        for (int bt = 0; bt < 4; bt++) {
            h8 bf = *(const h8*)(bp + bt*16*WD + ks*32);
            acc[0][bt] = MFMA(a0, bf, acc[0][bt]);
            acc[1][bt] = MFMA(a1, bf, acc[1][bt]);
        }
    }
    #pragma unroll
    for (int at = 0; at < 2; at++)
    #pragma unroll
    for (int bt = 0; bt < 4; bt++) {
        int col = c0 + wc*64 + bt*16 + ln;
        float bias = b3[col];
        int c = col / 300, t = col - c*300;
        #pragma unroll
        for (int r = 0; r < 4; r++) {
            int b = b0 + wr*32 + at*16 + lk*4 + r;
            float val = acc[at][bt][r] + bias;
            x[(long)b*NCOL + col] = val;
            xt[((long)b*TP + t)*WD + c] = (half_t)val;
        }
    }
}

// ---------------- rfft MFMA: S[m][b][ri*128+c] = sum_t x[(b,c)][t] * Fth[j][t] ----------------
__global__ __launch_bounds__(256) void k_rfft(const float* __restrict__ x, const half_t* __restrict__ Fth,
        half_t* __restrict__ S, int CB){
    int tid = threadIdx.x;
    int lane = tid & 63, w = tid >> 6;
    int ln = lane & 15, lk = lane >> 4;
    long r0 = (long)blockIdx.x*128 + w*32;
    f4 zz = {0.f,0.f,0.f,0.f};
    f4 acc[2][3];
    #pragma unroll
    for (int i = 0; i < 2; i++) for (int j = 0; j < 3; j++) acc[i][j] = zz;
    const half_t* fpB = Fth + ln*TP + lk*8;
    #pragma unroll
    for (int ks = 0; ks < 9; ks++) {
        int kb = ks*32 + lk*8;
        h8 a[2];
        #pragma unroll
        for (int at = 0; at < 2; at++) {
            const float* xp = x + (r0 + at*16 + ln)*TD + kb;
            float4 v0 = *(const float4*)(xp);
            float4 v1 = *(const float4*)(xp + 4);
            a[at][0]=(half_t)v0.x; a[at][1]=(half_t)v0.y; a[at][2]=(half_t)v0.z; a[at][3]=(half_t)v0.w;
            a[at][4]=(half_t)v1.x; a[at][5]=(half_t)v1.y; a[at][6]=(half_t)v1.z; a[at][7]=(half_t)v1.w;
        }
        #pragma unroll
        for (int jt = 0; jt < 3; jt++) {
            h8 bf = *(const h8*)(fpB + jt*16*TP + ks*32);
            acc[0][jt] = MFMA(a[0], bf, acc[0][jt]);
            acc[1][jt] = MFMA(a[1], bf, acc[1][jt]);
        }
    }
    {   // K tail: t = 288 + lk*8 + e, mask t >= 300
        int kb = 288 + lk*8;
        h8 a[2];
        #pragma unroll
        for (int at = 0; at < 2; at++) {
            const float* xp = x + (r0 + at*16 + ln)*TD;
            #pragma unroll
            for (int e = 0; e < 8; e++) {
                int k = kb + e;
                a[at][e] = (k < TD) ? (half_t)xp[k] : (half_t)0.0f;
            }
        }
        #pragma unroll
        for (int jt = 0; jt < 3; jt++) {
            h8 bf = *(const h8*)(fpB + jt*16*TP + 288);
            acc[0][jt] = MFMA(a[0], bf, acc[0][jt]);
            acc[1][jt] = MFMA(a[1], bf, acc[1][jt]);
        }
    }
    #pragma unroll
    for (int at = 0; at < 2; at++)
    #pragma unroll
    for (int jt = 0; jt < 3; jt++) {
        int j = jt*16 + ln;
        int m = j >> 1, ri = j & 1;
        #pragma unroll
        for (int r = 0; r < 4; r++) {
            long row = r0 + at*16 + lk*4 + r;
            int b = (int)(row >> 7), c = (int)(row & 127);
            S[((long)m*CB + b)*256 + ri*128 + c] = (half_t)acc[at][jt][r];
        }
    }
}

// ---------------- mix MFMA: per mode, [CB x 256] @ [256 x 256] ----------------
__global__ __launch_bounds__(256) void k_mix(const half_t* __restrict__ S, const half_t* __restrict__ Wxh,
        half_t* __restrict__ Yh, int layer, int CB){
    int tid = threadIdx.x;
    int lane = tid & 63, w = tid >> 6;
    int wr = w >> 1, wc = w & 1;
    int ln = lane & 15, lk = lane >> 4;
    int m = blockIdx.z;
    int b0 = blockIdx.x * 64;
    int n0 = blockIdx.y * 128;
    f4 zz = {0.f,0.f,0.f,0.f};
    f4 acc[2][4];
    #pragma unroll
    for (int i = 0; i < 2; i++) for (int j = 0; j < 4; j++) acc[i][j] = zz;
    const half_t* ap = S + ((long)m*CB + b0 + wr*32 + ln)*256 + lk*8;
    const half_t* bp = Wxh + (((long)(layer*NM + m))*256 + n0 + wc*64 + ln)*256 + lk*8;
    #pragma unroll
    for (int ks = 0; ks < 8; ks++) {
        h8 a0 = *(const h8*)(ap + ks*32);
        h8 a1 = *(const h8*)(ap + 16*256 + ks*32);
        #pragma unroll
        for (int bt = 0; bt < 4; bt++) {
            h8 bf = *(const h8*)(bp + bt*16*256 + ks*32);
            acc[0][bt] = MFMA(a0, bf, acc[0][bt]);
            acc[1][bt] = MFMA(a1, bf, acc[1][bt]);
        }
    }
    const float inv = 1.0f / WSCALE;
    #pragma unroll
    for (int at = 0; at < 2; at++)
    #pragma unroll
    for (int bt = 0; bt < 4; bt++) {
        int n = n0 + wc*64 + bt*16 + ln;
        int o = n & 127, ri = n >> 7;
        #pragma unroll
        for (int r = 0; r < 4; r++) {
            int b = b0 + wr*32 + at*16 + lk*4 + r;
            Yh[((long)b*WD + o)*NJP + 2*m + ri] = (half_t)(acc[at][bt][r] * inv);
        }
    }
}

// ---------------- fused irfft + conv + gelu + residual: K=192 concatenated GEMM ----------------
// A[o][k] = [cwh[l][o][c] | Yh[b][o][j]] ; B[t][k] = [xt_in[b][t][c] | Gt[t][j]]
__global__ __launch_bounds__(256) void k_fuse(const half_t* __restrict__ Yh, const half_t* __restrict__ Gt,
        const half_t* __restrict__ cwh, const half_t* __restrict__ xt_in, const float* __restrict__ convb,
        float* __restrict__ x, half_t* __restrict__ xt_out, int layer){
    int tid = threadIdx.x;
    int lane = tid & 63, w = tid >> 6;
    int wo = (w >> 1)*32, wt = (w & 1)*32;
    int ln = lane & 15, lk = lane >> 4;
    int t0 = blockIdx.x * 64, o0 = blockIdx.y * 64;
    long b = blockIdx.z;
    f4 zz = {0.f,0.f,0.f,0.f};
    f4 acc[2][2];
    #pragma unroll
    for (int i = 0; i < 2; i++) for (int j = 0; j < 2; j++) acc[i][j] = zz;
    // conv region: k 0..127
    const half_t* ap = cwh + ((long)layer*WD + o0 + wo + ln)*WD + lk*8;
    const half_t* bp = xt_in + (b*TP + t0 + wt + ln)*WD + lk*8;
    #pragma unroll
    for (int ks = 0; ks < 4; ks++) {
        h8 a0 = *(const h8*)(ap + ks*32);
        h8 a1 = *(const h8*)(ap + 16*WD + ks*32);
        h8 b0f = *(const h8*)(bp + ks*32);
        h8 b1f = *(const h8*)(bp + 16*WD + ks*32);
        acc[0][0] = MFMA(a0, b0f, acc[0][0]);
        acc[0][1] = MFMA(a0, b1f, acc[0][1]);
        acc[1][0] = MFMA(a1, b0f, acc[1][0]);
        acc[1][1] = MFMA(a1, b1f, acc[1][1]);
    }
    // irfft region: k 128..191 (j 0..63; Yh pad j>=48 garbage x Gt zeros -> 0)
    const half_t* ap2 = Yh + (b*WD + o0 + wo + ln)*NJP + lk*8;
    const half_t* bp2 = Gt + (long)(t0 + wt + ln)*NJP + lk*8;
    #pragma unroll
    for (int ks = 0; ks < 2; ks++) {
        h8 a0 = *(const h8*)(ap2 + ks*32);
        h8 a1 = *(const h8*)(ap2 + 16*NJP + ks*32);
        h8 b0f = *(const h8*)(bp2 + ks*32);
        h8 b1f = *(const h8*)(bp2 + 16*NJP + ks*32);
        acc[0][0] = MFMA(a0, b0f, acc[0][0]);
        acc[0][1] = MFMA(a0, b1f, acc[0][1]);
        acc[1][0] = MFMA(a1, b0f, acc[1][0]);
        acc[1][1] = MFMA(a1, b1f, acc[1][1]);
    }
    #pragma unroll
    for (int at = 0; at < 2; at++)
    #pragma unroll
    for (int bt = 0; bt < 2; bt++) {
        int t = t0 + wt + bt*16 + ln;
        if (t >= TD) continue;
        int obase = o0 + wo + at*16 + lk*4;
        h4v hv;
        #pragma unroll
        for (int r = 0; r < 4; r++) {
            int o = obase + r;
            float v = acc[at][bt][r] + convb[layer*WD + o];
            long xi = b*NCOL + (long)o*TD + t;
            float outv = gelu_f(v) + x[xi];
            x[xi] = outv;
            hv[r] = (half_t)outv;
        }
        *(h4v*)(xt_out + (b*TP + t)*WD + obase) = hv;
    }
}

// ---------------- output projection (fp32) ----------------
__global__ __launch_bounds__(320) void k_out(const float* __restrict__ x,
        const float* __restrict__ w1, const float* __restrict__ b1,
        const float* __restrict__ w2, const float* __restrict__ b2,
        float* __restrict__ out){
    __shared__ float w1t[WD*64];
    __shared__ float w2l[192];
    __shared__ float b1l[64];
    int tid = threadIdx.x;
    long b = blockIdx.x;
    for (int idx = tid; idx < WD*64; idx += 320) {
        int o = idx & 63, c = idx >> 6;
        w1t[c*64 + o] = w1[o*WD + c];
    }
    if (tid < 192) w2l[tid] = w2[tid];
    if (tid < 64) b1l[tid] = b1[tid];
    __syncthreads();
    int t = tid;
    if (t >= TD) return;
    const float* xb = x + b*WD*TD;
    float hc[64];
    #pragma unroll
    for (int k = 0; k < 64; k++) hc[k] = b1l[k];
    for (int c = 0; c < WD; c++) {
        float xv = xb[c*TD + t];
        #pragma unroll
        for (int k = 0; k < 64; k += 4) {
            float4 w4 = *(const float4*)(&w1t[c*64 + k]);
            hc[k]   += w4.x*xv;
            hc[k+1] += w4.y*xv;
            hc[k+2] += w4.z*xv;
            hc[k+3] += w4.w*xv;
        }
    }
    float r0 = b2[0], r1 = b2[1], r2 = b2[2];
    #pragma unroll
    for (int k = 0; k < 64; k++) {
        float g = gelu_f(hc[k]);
        r0 += w2l[k]     * g;
        r1 += w2l[64+k]  * g;
        r2 += w2l[128+k] * g;
    }
    long ob = (b*TD + t)*3;
    out[ob+0] = r0; out[ob+1] = r1; out[ob+2] = r2;
}

extern "C" void kernel_launch(void* const* d_in, const int* in_sizes, int n_in,
                              void* d_out, int out_size, void* d_ws, size_t ws_size,
                              hipStream_t stream) {
    const float* params = (const float*)d_in[0];
    const float* enc_w1 = (const float*)d_in[1];
    const float* enc_b1 = (const float*)d_in[2];
    const float* enc_w2 = (const float*)d_in[3];
    const float* enc_b2 = (const float*)d_in[4];
    const float* enc_w3 = (const float*)d_in[5];
    const float* enc_b3 = (const float*)d_in[6];
    const float* spec_wr = (const float*)d_in[7];
    const float* spec_wi = (const float*)d_in[8];
    const float* conv_w  = (const float*)d_in[9];
    const float* conv_b  = (const float*)d_in[10];
    const float* out_w1  = (const float*)d_in[11];
    const float* out_b1  = (const float*)d_in[12];
    const float* out_w2  = (const float*)d_in[13];
    const float* out_b2  = (const float*)d_in[14];
    float* outp = (float*)d_out;

    // fixed-size buffers (bytes, all 256-aligned)
    const long szWxh = (long)NL*NM*256*256*2;   // 18,874,368
    const long szW3t = (long)NCOL*WD*2;         //  9,830,400
    const long szCwh = (long)NL*WD*WD*2;        //    196,608
    const long szFth = (long)NJ*TP*2;           //     30,720
    const long szGt  = (long)TP*NJP*2;          //     40,960
    const long fixedB = szWxh + szW3t + szCwh + szFth + szGt;
    // per-sample bytes: x + xt0 + xt1 + S + Yh + h1 + h2h
    const long perCB = (long)NCOL*4 + 2L*TP*WD*2 + (long)NM*256*2 + (long)WD*NJP*2 + WD*4 + WD*2;

    long CB = 2048; int nchunk = 1;
    while (CB > 64 && fixedB + CB*perCB > (long)ws_size) { CB >>= 1; nchunk <<= 1; }

    char* p = (char*)d_ws;
    half_t* Wxh = (half_t*)p; p += szWxh;
    half_t* w3t = (half_t*)p; p += szW3t;
    half_t* cwh = (half_t*)p; p += szCwh;
    half_t* Fth = (half_t*)p; p += szFth;
    half_t* Gt  = (half_t*)p; p += szGt;
    float*  x   = (float*)p;  p += CB*(long)NCOL*4;
    half_t* xt0 = (half_t*)p; p += CB*(long)TP*WD*2;
    half_t* xt1 = (half_t*)p; p += CB*(long)TP*WD*2;
    half_t* S   = (half_t*)p; p += CB*(long)NM*256*2;
    half_t* Yh  = (half_t*)p; p += CB*(long)WD*NJP*2;
    float*  h1  = (float*)p;  p += CB*(long)WD*4;
    half_t* h2h = (half_t*)p; p += CB*(long)WD*2;

    k_tables<<<80, 256, 0, stream>>>(Fth, Gt);
    k_wx<<<36864, 256, 0, stream>>>(spec_wr, spec_wi, Wxh);
    k_w3t<<<19200, 256, 0, stream>>>(enc_w3, w3t);
    k_cwh<<<384, 256, 0, stream>>>(conv_w, cwh);

    for (int ch = 0; ch < nchunk; ch++) {
        const float* pch = params + (long)ch*CB*5;
        float* outch = outp + (long)ch*CB*TD*3;
        k_enc1<<<(int)(CB*WD/256), 256, 0, stream>>>(pch, enc_w1, enc_b1, h1);
        k_enc2<<<(int)(CB*WD/256), 256, 0, stream>>>(h1, enc_w2, enc_b2, h2h);
        k_enc3<<<dim3(NCOL/128, (int)(CB/64)), 256, 0, stream>>>(h2h, w3t, enc_b3, x, xt0);
        for (int l = 0; l < NL; l++) {
            half_t* xin  = (l & 1) ? xt1 : xt0;
            half_t* xout = (l & 1) ? xt0 : xt1;
            k_rfft<<<(int)CB, 256, 0, stream>>>(x, Fth, S, (int)CB);
            k_mix<<<dim3((int)(CB/64), 2, NM), 256, 0, stream>>>(S, Wxh, Yh, l, (int)CB);
            k_fuse<<<dim3(TP/64, 2, (int)CB), 256, 0, stream>>>(Yh, Gt, cwh, xin, conv_b, x, xout, l);
        }
        k_out<<<(int)CB, 320, 0, stream>>>(x, out_w1, out_b1, out_w2, out_b2, outch);
    }
}

// Round 4
// 4834.384 us; speedup vs baseline: 4.3440x; 1.0637x over previous
//
#include <hip/hip_runtime.h>
#include <math.h>

#define NB 2048
#define WD 128
#define TD 300
#define TP 320
#define NM 24
#define NJ 48
#define NJP 64
#define NL 6
#define NCOL 38400
#define WSCALE 1024.0f

typedef _Float16 half_t;
typedef _Float16 h8 __attribute__((ext_vector_type(8)));
typedef _Float16 h4v __attribute__((ext_vector_type(4)));
typedef float f4 __attribute__((ext_vector_type(4)));

#define MFMA(a,b,c) __builtin_amdgcn_mfma_f32_16x16x32_f16(a,b,c,0,0,0)

__device__ __forceinline__ float gelu_f(float v){
    return 0.5f * v * (1.0f + erff(v * 0.70710678118654752f));
}

// ---------------- DFT basis tables (fp16) ----------------
// Fth[j][t] (48x320): j=2m -> cos(2pi m t/300), j=2m+1 -> -sin ; t>=300 -> 0
// Gt[t][j]  (320x64): j=2m -> s_m cos, j=2m+1 -> -s_m sin (0 for m=0); j>=48 -> 0
__global__ __launch_bounds__(256) void k_tables(half_t* __restrict__ Fth, half_t* __restrict__ Gt){
    int idx = blockIdx.x*256 + threadIdx.x;
    const float w0 = 6.28318530717958647692f / 300.0f;
    if (idx < NJ*TP) {
        int j = idx / TP, t = idx - j*TP;
        int m = j >> 1;
        float v = 0.0f;
        if (t < TD) {
            int r = (m*t) % TD;
            float ang = (float)r * w0;
            v = (j & 1) ? -sinf(ang) : cosf(ang);
        }
        Fth[idx] = (half_t)v;
    }
    if (idx < TP*NJP) {
        int t = idx / NJP, j = idx - t*NJP;
        float v = 0.0f;
        if (j < NJ) {
            int m = j >> 1;
            int r = (m * (t % TD)) % TD;
            float ang = (float)r * w0;
            float s = (m == 0) ? (1.0f/300.0f) : (2.0f/300.0f);
            if (j & 1) v = (m == 0) ? 0.0f : -s*sinf(ang);
            else       v = s*cosf(ang);
        }
        Gt[idx] = (half_t)v;
    }
}

// ---------------- expanded complex weights: Wxh[l][m][n][k] fp16, x WSCALE ----------------
__global__ __launch_bounds__(256) void k_wx(const float* __restrict__ wr, const float* __restrict__ wi,
                                            half_t* __restrict__ Wxh){
    long idx = (long)blockIdx.x*256 + threadIdx.x;
    if (idx >= (long)NL*NM*256*256) return;
    int k = (int)(idx & 255), n = (int)((idx >> 8) & 255);
    int lm = (int)(idx >> 16);
    int l = lm / NM, m = lm - l*NM;
    int i = k & 127, o = n & 127;
    long src = (((long)(l*WD + i))*WD + o)*NM + m;
    float v;
    if (n < 128) v = (k < 128) ? wr[src] : -wi[src];
    else         v = (k < 128) ? wi[src] :  wr[src];
    Wxh[idx] = (half_t)(v * WSCALE);
}

__global__ __launch_bounds__(256) void k_w3t(const float* __restrict__ w3, half_t* __restrict__ w3t){
    int idx = blockIdx.x*256 + threadIdx.x;
    if (idx >= NCOL*WD) return;
    int k = idx & 127, col = idx >> 7;
    w3t[idx] = (half_t)w3[k*NCOL + col];
}

__global__ __launch_bounds__(256) void k_cwh(const float* __restrict__ cw, half_t* __restrict__ cwh){
    int idx = blockIdx.x*256 + threadIdx.x;
    if (idx >= NL*WD*WD) return;
    cwh[idx] = (half_t)cw[idx];
}

__global__ __launch_bounds__(256) void k_w1h(const float* __restrict__ w1, half_t* __restrict__ w1h){
    int idx = blockIdx.x*256 + threadIdx.x;
    if (idx >= 64*WD) return;
    w1h[idx] = (half_t)w1[idx];
}

// ---------------- encoder ----------------
__global__ __launch_bounds__(256) void k_enc1(const float* __restrict__ p, const float* __restrict__ w1,
                                              const float* __restrict__ b1, float* __restrict__ h1){
    int idx = blockIdx.x*256 + threadIdx.x;
    int b = idx >> 7, k = idx & 127;
    float acc = b1[k];
    #pragma unroll
    for (int j = 0; j < 5; j++) acc += p[b*5+j] * w1[j*WD+k];
    h1[idx] = gelu_f(acc);
}

__global__ __launch_bounds__(256) void k_enc2(const float* __restrict__ h1, const float* __restrict__ w2,
                                              const float* __restrict__ b2, half_t* __restrict__ h2h){
    int idx = blockIdx.x*256 + threadIdx.x;
    int b = idx >> 7, k = idx & 127;
    const float* row = h1 + b*WD;
    float acc = b2[k];
    for (int j = 0; j < WD; j += 4) {
        float4 h4 = *(const float4*)(row + j);
        acc += h4.x * w2[(j+0)*WD+k] + h4.y * w2[(j+1)*WD+k]
             + h4.z * w2[(j+2)*WD+k] + h4.w * w2[(j+3)*WD+k];
    }
    h2h[idx] = (half_t)gelu_f(acc);
}

// ---------------- enc3 MFMA: writes x fp32, xt fp16 [b][t][c], xc fp16 [b][c][t] ----------------
__global__ __launch_bounds__(256) void k_enc3(const half_t* __restrict__ h2h, const half_t* __restrict__ w3t,
        const float* __restrict__ b3, float* __restrict__ x, half_t* __restrict__ xt, half_t* __restrict__ xc){
    int tid = threadIdx.x;
    int lane = tid & 63, w = tid >> 6;
    int wr = w >> 1, wc = w & 1;
    int c0 = blockIdx.x * 128;
    int b0 = blockIdx.y * 64;
    int ln = lane & 15, lk = lane >> 4;
    f4 zz = {0.f,0.f,0.f,0.f};
    f4 acc[2][4];
    #pragma unroll
    for (int i = 0; i < 2; i++) for (int j = 0; j < 4; j++) acc[i][j] = zz;
    const half_t* ap = h2h + (long)(b0 + wr*32 + ln)*WD + lk*8;
    const half_t* bp = w3t + (long)(c0 + wc*64 + ln)*WD + lk*8;
    #pragma unroll
    for (int ks = 0; ks < 4; ks++) {
        h8 a0 = *(const h8*)(ap + ks*32);
        h8 a1 = *(const h8*)(ap + 16*WD + ks*32);
        #pragma unroll
        for (int bt = 0; bt < 4; bt++) {
            h8 bf = *(const h8*)(bp + bt*16*WD + ks*32);
            acc[0][bt] = MFMA(a0, bf, acc[0][bt]);
            acc[1][bt] = MFMA(a1, bf, acc[1][bt]);
        }
    }
    #pragma unroll
    for (int at = 0; at < 2; at++)
    #pragma unroll
    for (int bt = 0; bt < 4; bt++) {
        int col = c0 + wc*64 + bt*16 + ln;
        float bias = b3[col];
        int c = col / 300, t = col - c*300;
        #pragma unroll
        for (int r = 0; r < 4; r++) {
            int b = b0 + wr*32 + at*16 + lk*4 + r;
            float val = acc[at][bt][r] + bias;
            x[(long)b*NCOL + col] = val;
            xt[((long)b*TP + t)*WD + c] = (half_t)val;
            xc[((long)b*WD + c)*TP + t] = (half_t)val;
        }
    }
}

// ---------------- rfft MFMA from xc (fp16, K=t=320 padded) ----------------
__global__ __launch_bounds__(256) void k_rfft(const half_t* __restrict__ xc, const half_t* __restrict__ Fth,
        half_t* __restrict__ S, int CB){
    int tid = threadIdx.x;
    int lane = tid & 63, w = tid >> 6;
    int ln = lane & 15, lk = lane >> 4;
    long r0 = (long)blockIdx.x*128 + w*32;
    f4 zz = {0.f,0.f,0.f,0.f};
    f4 acc[2][3];
    #pragma unroll
    for (int i = 0; i < 2; i++) for (int j = 0; j < 3; j++) acc[i][j] = zz;
    const half_t* ap = xc + r0*TP + lk*8;
    const half_t* fpB = Fth + ln*TP + lk*8;
    #pragma unroll
    for (int ks = 0; ks < 10; ks++) {
        h8 a0 = *(const h8*)(ap + ln*TP + ks*32);
        h8 a1 = *(const h8*)(ap + (16+ln)*TP + ks*32);
        #pragma unroll
        for (int jt = 0; jt < 3; jt++) {
            h8 bf = *(const h8*)(fpB + jt*16*TP + ks*32);
            acc[0][jt] = MFMA(a0, bf, acc[0][jt]);
            acc[1][jt] = MFMA(a1, bf, acc[1][jt]);
        }
    }
    #pragma unroll
    for (int at = 0; at < 2; at++)
    #pragma unroll
    for (int jt = 0; jt < 3; jt++) {
        int j = jt*16 + ln;
        int m = j >> 1, ri = j & 1;
        #pragma unroll
        for (int r = 0; r < 4; r++) {
            long row = r0 + at*16 + lk*4 + r;
            int b = (int)(row >> 7), c = (int)(row & 127);
            S[((long)m*CB + b)*256 + ri*128 + c] = (half_t)acc[at][jt][r];
        }
    }
}

// ---------------- mix MFMA: per mode, [CB x 256] @ [256 x 256] ----------------
__global__ __launch_bounds__(256) void k_mix(const half_t* __restrict__ S, const half_t* __restrict__ Wxh,
        half_t* __restrict__ Yh, int layer, int CB){
    int tid = threadIdx.x;
    int lane = tid & 63, w = tid >> 6;
    int wr = w >> 1, wc = w & 1;
    int ln = lane & 15, lk = lane >> 4;
    int m = blockIdx.z;
    int b0 = blockIdx.x * 64;
    int n0 = blockIdx.y * 128;
    f4 zz = {0.f,0.f,0.f,0.f};
    f4 acc[2][4];
    #pragma unroll
    for (int i = 0; i < 2; i++) for (int j = 0; j < 4; j++) acc[i][j] = zz;
    const half_t* ap = S + ((long)m*CB + b0 + wr*32 + ln)*256 + lk*8;
    const half_t* bp = Wxh + (((long)(layer*NM + m))*256 + n0 + wc*64 + ln)*256 + lk*8;
    #pragma unroll
    for (int ks = 0; ks < 8; ks++) {
        h8 a0 = *(const h8*)(ap + ks*32);
        h8 a1 = *(const h8*)(ap + 16*256 + ks*32);
        #pragma unroll
        for (int bt = 0; bt < 4; bt++) {
            h8 bf = *(const h8*)(bp + bt*16*256 + ks*32);
            acc[0][bt] = MFMA(a0, bf, acc[0][bt]);
            acc[1][bt] = MFMA(a1, bf, acc[1][bt]);
        }
    }
    const float inv = 1.0f / WSCALE;
    #pragma unroll
    for (int at = 0; at < 2; at++)
    #pragma unroll
    for (int bt = 0; bt < 4; bt++) {
        int n = n0 + wc*64 + bt*16 + ln;
        int o = n & 127, ri = n >> 7;
        #pragma unroll
        for (int r = 0; r < 4; r++) {
            int b = b0 + wr*32 + at*16 + lk*4 + r;
            Yh[((long)b*WD + o)*NJP + 2*m + ri] = (half_t)(acc[at][bt][r] * inv);
        }
    }
}

// ---------------- fused irfft + conv + gelu + residual, IN-PLACE on xt ----------------
// block owns (b, t-tile 64, ALL o). A=[cwh|Yh] rows o, B=[xt|Gt] rows t, K=128+64.
__global__ __launch_bounds__(256) void k_fuse(const half_t* __restrict__ Yh, const half_t* __restrict__ Gt,
        const half_t* __restrict__ cwh, half_t* __restrict__ xt, const float* __restrict__ convb,
        float* __restrict__ x, half_t* __restrict__ xc, int layer){
    int tid = threadIdx.x;
    int lane = tid & 63, w = tid >> 6;
    int wo = w * 32;
    int ln = lane & 15, lk = lane >> 4;
    int t0 = blockIdx.x * 64;
    long b = blockIdx.y;
    f4 zz = {0.f,0.f,0.f,0.f};
    f4 acc[2][4];
    #pragma unroll
    for (int i = 0; i < 2; i++) for (int j = 0; j < 4; j++) acc[i][j] = zz;
    // conv region: K = c 0..127
    const half_t* ap = cwh + ((long)layer*WD + wo + ln)*WD + lk*8;
    const half_t* bp = xt + (b*TP + t0 + ln)*WD + lk*8;
    #pragma unroll
    for (int ks = 0; ks < 4; ks++) {
        h8 a0 = *(const h8*)(ap + ks*32);
        h8 a1 = *(const h8*)(ap + 16*WD + ks*32);
        #pragma unroll
        for (int bt = 0; bt < 4; bt++) {
            h8 bf = *(const h8*)(bp + bt*16*WD + ks*32);
            acc[0][bt] = MFMA(a0, bf, acc[0][bt]);
            acc[1][bt] = MFMA(a1, bf, acc[1][bt]);
        }
    }
    // irfft region: K = j 0..63 (Yh[j>=48] garbage x Gt zeros -> 0)
    const half_t* ap2 = Yh + (b*WD + wo + ln)*NJP + lk*8;
    const half_t* bp2 = Gt + (long)(t0 + ln)*NJP + lk*8;
    #pragma unroll
    for (int ks = 0; ks < 2; ks++) {
        h8 a0 = *(const h8*)(ap2 + ks*32);
        h8 a1 = *(const h8*)(ap2 + 16*NJP + ks*32);
        #pragma unroll
        for (int bt = 0; bt < 4; bt++) {
            h8 bf = *(const h8*)(bp2 + bt*16*NJP + ks*32);
            acc[0][bt] = MFMA(a0, bf, acc[0][bt]);
            acc[1][bt] = MFMA(a1, bf, acc[1][bt]);
        }
    }
    __syncthreads();   // all xt reads complete before in-place writes
    #pragma unroll
    for (int at = 0; at < 2; at++)
    #pragma unroll
    for (int bt = 0; bt < 4; bt++) {
        int t = t0 + bt*16 + ln;
        if (t >= TD) continue;
        int obase = wo + at*16 + lk*4;
        h4v hv;
        #pragma unroll
        for (int r = 0; r < 4; r++) {
            int o = obase + r;
            float v = acc[at][bt][r] + convb[layer*WD + o];
            long xi = b*NCOL + (long)o*TD + t;
            float outv = gelu_f(v) + x[xi];
            x[xi] = outv;
            hv[r] = (half_t)outv;
            xc[(b*WD + o)*TP + t] = (half_t)outv;
        }
        *(h4v*)(xt + (b*TP + t)*WD + obase) = hv;
    }
}

// ---------------- output projection MFMA: A=w1h [64][128], B=xt, epilogue via LDS ----------------
__global__ __launch_bounds__(256) void k_out(const half_t* __restrict__ xt, const half_t* __restrict__ w1h,
        const float* __restrict__ b1, const float* __restrict__ w2, const float* __restrict__ b2,
        float* __restrict__ out){
    __shared__ float gl[64*68];   // [t][o] padded
    __shared__ float w2l[192];
    int tid = threadIdx.x;
    int lane = tid & 63, w = tid >> 6;
    int mo = (w >> 1)*32, mt = (w & 1)*32;
    int ln = lane & 15, lk = lane >> 4;
    int t0 = blockIdx.x * 64;
    long b = blockIdx.y;
    f4 zz = {0.f,0.f,0.f,0.f};
    f4 acc[2][2];
    #pragma unroll
    for (int i = 0; i < 2; i++) for (int j = 0; j < 2; j++) acc[i][j] = zz;
    const half_t* ap = w1h + (long)(mo + ln)*WD + lk*8;
    const half_t* bp = xt + (b*TP + t0 + mt + ln)*WD + lk*8;
    #pragma unroll
    for (int ks = 0; ks < 4; ks++) {
        h8 a0 = *(const h8*)(ap + ks*32);
        h8 a1 = *(const h8*)(ap + 16*WD + ks*32);
        h8 b0f = *(const h8*)(bp + ks*32);
        h8 b1f = *(const h8*)(bp + 16*WD + ks*32);
        acc[0][0] = MFMA(a0, b0f, acc[0][0]);
        acc[0][1] = MFMA(a0, b1f, acc[0][1]);
        acc[1][0] = MFMA(a1, b0f, acc[1][0]);
        acc[1][1] = MFMA(a1, b1f, acc[1][1]);
    }
    if (tid < 192) w2l[tid] = w2[tid];
    #pragma unroll
    for (int at = 0; at < 2; at++)
    #pragma unroll
    for (int bt = 0; bt < 2; bt++) {
        int tl = mt + bt*16 + ln;
        int obase = mo + at*16 + lk*4;
        #pragma unroll
        for (int r = 0; r < 4; r++) {
            int o = obase + r;
            gl[tl*68 + o] = gelu_f(acc[at][bt][r] + b1[o]);
        }
    }
    __syncthreads();
    int t = tid & 63, q = tid >> 6;
    int tg = t0 + t;
    if (q < 3 && tg < TD) {
        float s = b2[q];
        const float* gr = &gl[t*68];
        const float* wr = &w2l[q*64];
        #pragma unroll
        for (int o = 0; o < 64; o += 4) {
            s += wr[o]*gr[o] + wr[o+1]*gr[o+1] + wr[o+2]*gr[o+2] + wr[o+3]*gr[o+3];
        }
        out[((long)b*TD + tg)*3 + q] = s;
    }
}

extern "C" void kernel_launch(void* const* d_in, const int* in_sizes, int n_in,
                              void* d_out, int out_size, void* d_ws, size_t ws_size,
                              hipStream_t stream) {
    const float* params = (const float*)d_in[0];
    const float* enc_w1 = (const float*)d_in[1];
    const float* enc_b1 = (const float*)d_in[2];
    const float* enc_w2 = (const float*)d_in[3];
    const float* enc_b2 = (const float*)d_in[4];
    const float* enc_w3 = (const float*)d_in[5];
    const float* enc_b3 = (const float*)d_in[6];
    const float* spec_wr = (const float*)d_in[7];
    const float* spec_wi = (const float*)d_in[8];
    const float* conv_w  = (const float*)d_in[9];
    const float* conv_b  = (const float*)d_in[10];
    const float* out_w1  = (const float*)d_in[11];
    const float* out_b1  = (const float*)d_in[12];
    const float* out_w2  = (const float*)d_in[13];
    const float* out_b2  = (const float*)d_in[14];
    float* outp = (float*)d_out;

    // fixed buffers (bytes)
    const long szWxh = (long)NL*NM*256*256*2;   // 18,874,368
    const long szW3t = (long)NCOL*WD*2;         //  9,830,400
    const long szCwh = (long)NL*WD*WD*2;        //    196,608
    const long szW1h = (long)64*WD*2;           //     16,384
    const long szFth = (long)NJ*TP*2;           //     30,720
    const long szGt  = (long)TP*NJP*2;          //     40,960
    const long fixedB = szWxh + szW3t + szCwh + szW1h + szFth + szGt;
    // per-sample bytes: x + xt + xc + S + Yh + h1 + h2h
    const long perCB = (long)NCOL*4 + (long)TP*WD*2*2 + (long)NM*256*2 + (long)WD*NJP*2 + WD*4 + WD*2;

    // CB=512 keeps the chunk working set (~207 MB) inside the 256 MB Infinity Cache
    long CB = 512; 
    while (CB > 64 && fixedB + CB*perCB > (long)ws_size) CB >>= 1;
    int nchunk = (int)(NB / CB);

    char* p = (char*)d_ws;
    half_t* Wxh = (half_t*)p; p += szWxh;
    half_t* w3t = (half_t*)p; p += szW3t;
    half_t* cwh = (half_t*)p; p += szCwh;
    half_t* w1h = (half_t*)p; p += szW1h;
    half_t* Fth = (half_t*)p; p += szFth;
    half_t* Gt  = (half_t*)p; p += szGt;
    float*  x   = (float*)p;  p += CB*(long)NCOL*4;
    half_t* xt  = (half_t*)p; p += CB*(long)TP*WD*2;
    half_t* xc  = (half_t*)p; p += CB*(long)TP*WD*2;
    half_t* S   = (half_t*)p; p += CB*(long)NM*256*2;
    half_t* Yh  = (half_t*)p; p += CB*(long)WD*NJP*2;
    float*  h1  = (float*)p;  p += CB*(long)WD*4;
    half_t* h2h = (half_t*)p; p += CB*(long)WD*2;

    k_tables<<<80, 256, 0, stream>>>(Fth, Gt);
    k_wx<<<36864, 256, 0, stream>>>(spec_wr, spec_wi, Wxh);
    k_w3t<<<19200, 256, 0, stream>>>(enc_w3, w3t);
    k_cwh<<<384, 256, 0, stream>>>(conv_w, cwh);
    k_w1h<<<32, 256, 0, stream>>>(out_w1, w1h);

    for (int ch = 0; ch < nchunk; ch++) {
        const float* pch = params + (long)ch*CB*5;
        float* outch = outp + (long)ch*CB*TD*3;
        k_enc1<<<(int)(CB*WD/256), 256, 0, stream>>>(pch, enc_w1, enc_b1, h1);
        k_enc2<<<(int)(CB*WD/256), 256, 0, stream>>>(h1, enc_w2, enc_b2, h2h);
        k_enc3<<<dim3(NCOL/128, (int)(CB/64)), 256, 0, stream>>>(h2h, w3t, enc_b3, x, xt, xc);
        for (int l = 0; l < NL; l++) {
            k_rfft<<<(int)CB, 256, 0, stream>>>(xc, Fth, S, (int)CB);
            k_mix<<<dim3((int)(CB/64), 2, NM), 256, 0, stream>>>(S, Wxh, Yh, l, (int)CB);
            k_fuse<<<dim3(TP/64, (int)CB), 256, 0, stream>>>(Yh, Gt, cwh, xt, conv_b, x, xc, l);
        }
        k_out<<<dim3(TP/64, (int)CB), 256, 0, stream>>>(xt, w1h, out_b1, out_w2, out_b2, outch);
    }
}